// Round 6
// baseline (151.260 us; speedup 1.0000x reference)
//
#include <hip/hip_runtime.h>
#include <math.h>

#define NA   21
#define NM   64
#define ND   210
#define DP   224            // padded descriptor row
#define NT   8192
#define KS2  32             // stage2 K-splits (256 t each)

#define QC 0.22360679774997896f   // sqrt(5)/10
#define KE 0.016666666666666666f  // 5/(3*sig^2)

typedef short bf8 __attribute__((ext_vector_type(8)));   // 8 bf16 (4 VGPRs)
typedef float f4  __attribute__((ext_vector_type(4)));   // 4 fp32 acc

// ---- workspace layout (float offsets); bf16 arrays count elems/2 ----
#define O_X16  0u              // Xp16 [8192][224] bf16  -> 917504 fl
#define O_J16  917504u         // Jp16
#define O_XT16 1835008u        // XpT16 [224][8192] bf16 -> 917504 fl
#define O_JT16 2752512u        // JpT16
#define O_W1   3670016u        // w1 [64][8192] bf16 -> 262144 fl
#define O_E1   3932160u        // e1
#define O_A16  4194304u        // A16 [64][224] bf16 -> 7168 fl
#define O_QG   4201472u        // qxsG fp32 [56][64][4] -> 14336 fl
#define O_NTT  4215808u        // nt [8192]
#define O_CJ   4224000u        // cJ [8192]
#define O_NX   4232192u        // [64]
#define O_ES   4232256u        // [64]
#define O_WA   4232320u        // [64]
#define O_AB   4232384u        // [2][64][224] fp32 = 28672
#define O_PB   4261056u        // Pbuf [32][2][64][224] fp32 = 917504  (ends 5178560 = 20.7 MB)

__device__ __forceinline__ unsigned short f2bf(float f) {
    unsigned u = __float_as_uint(f);
    u += 0x7fffu + ((u >> 16) & 1u);
    return (unsigned short)(u >> 16);
}
__device__ __forceinline__ float bf2f(unsigned short h) {
    return __uint_as_float((unsigned)h << 16);
}

__device__ __forceinline__ void d_to_ij(int d, int& i, int& j) {
    int ii = (int)((1.0f + sqrtf(1.0f + 8.0f * (float)d)) * 0.5f);
    while (ii * (ii - 1) / 2 > d) --ii;
    while ((ii + 1) * ii / 2 <= d) ++ii;
    i = ii;
    j = d - ii * (ii - 1) / 2;
}

// Fused prep. Roles by blockIdx.x:
//  [0,1792)      pad+convert -> Xp16/Jp16 [t][224] bf16 (Xp scaled by QC)
//  [1792,2816)   transpose   -> XpT16/JpT16 [224][8192] bf16 (64x64 tiles)
//  [2816,2880)   geom        -> A16, qxsG, nx (from rounded values)
//  [2880,3392)   rowstats    -> nt, cJ (from rounded values)
//  [3392,3393)   zero Es/Wa
__global__ __launch_bounds__(256) void k_prep(
    const float* __restrict__ Rs, const float* __restrict__ xs,
    const float* __restrict__ Jx,
    unsigned short* __restrict__ X16, unsigned short* __restrict__ J16,
    unsigned short* __restrict__ XT16, unsigned short* __restrict__ JT16,
    unsigned short* __restrict__ A16, float* __restrict__ qxsG,
    float* __restrict__ nx, float* __restrict__ nt, float* __restrict__ cJ,
    float* __restrict__ zbase) {
    const int b = blockIdx.x, tid = threadIdx.x;
    if (b < 1792) {                        // ---- pad+convert, 8 elems/thread
        int idx = b * 256 + tid;           // < 2*8192*28
        int arr = idx / (NT * 28);
        int r = idx - arr * (NT * 28);
        int t = r / 28, c = r - t * 28;
        int d = c * 8;
        const float* src = (arr ? Jx : xs) + (size_t)t * ND;
        float sc = arr ? 1.0f : QC;
        union { unsigned short us[8]; uint4 v; } u;
#pragma unroll
        for (int i = 0; i < 8; ++i) {
            float val = (d + i < ND) ? sc * src[d + i] : 0.0f;
            u.us[i] = f2bf(val);
        }
        unsigned short* dst = (arr ? J16 : X16) + (size_t)t * DP + d;
        *(uint4*)dst = u.v;
    } else if (b < 2816) {                 // ---- transpose 64x64 tiles
        int bb = b - 1792;
        int arr = bb >> 9;                 // 512 blocks each
        int r2 = bb & 511;
        int dt = r2 >> 7;                  // 0..3 (d-tiles of 64)
        int t0 = (r2 & 127) * 64;
        int d0 = dt * 64;
        const float* src = arr ? Jx : xs;
        unsigned short* dst = arr ? JT16 : XT16;
        float sc = arr ? 1.0f : QC;
        __shared__ float tile[64][65];
#pragma unroll
        for (int k = 0; k < 16; ++k) {
            int lin = k * 256 + tid;       // < 4096
            int tt = lin >> 6, dd = lin & 63;
            int d = d0 + dd;
            tile[tt][dd] = (d < ND) ? src[(size_t)(t0 + tt) * ND + d] : 0.0f;
        }
        __syncthreads();
#pragma unroll
        for (int k = 0; k < 16; ++k) {
            int lin = k * 256 + tid;
            int dd = lin >> 6, tt = lin & 63;
            int d = d0 + dd;
            if (d < DP) dst[(size_t)d * NT + t0 + tt] = f2bf(sc * tile[tt][dd]);
        }
    } else if (b < 2880) {                 // ---- geom: m = b-2816
        int m = b - 2816;
        __shared__ float R[NA * 3];
        __shared__ float red[256];
        if (tid < NA * 3) R[tid] = Rs[m * NA * 3 + tid];
        __syncthreads();
        float local = 0.0f;
        if (tid < DP) {
            float vr = 0.0f;
            unsigned short hv = 0;
            if (tid < ND) {
                int i, j; d_to_ij(tid, i, j);
                float dx = R[i * 3] - R[j * 3];
                float dy = R[i * 3 + 1] - R[j * 3 + 1];
                float dz = R[i * 3 + 2] - R[j * 3 + 2];
                float v = QC / sqrtf(dx * dx + dy * dy + dz * dz);
                hv = f2bf(v);
                vr = bf2f(hv);
            }
            A16[m * DP + tid] = hv;
            qxsG[(tid >> 2) * 256 + m * 4 + (tid & 3)] = vr;
            local = vr * vr;
        }
        red[tid] = local;
        __syncthreads();
        for (int s = 128; s > 0; s >>= 1) {
            if (tid < s) red[tid] += red[tid + s];
            __syncthreads();
        }
        if (tid == 0) nx[m] = red[0];
    } else if (b < 3392) {                 // ---- rowstats: 16 lanes per t
        int t = (b - 2880) * 16 + (tid >> 4);
        int l = tid & 15;
        const float* xr = xs + (size_t)t * ND;
        const float* jr = Jx + (size_t)t * ND;
        float sn = 0.0f, sc = 0.0f;
        for (int c = l; c < ND; c += 16) {
            float x = bf2f(f2bf(QC * xr[c]));
            float j = bf2f(f2bf(jr[c]));
            sn = fmaf(x, x, sn);
            sc = fmaf(x, j, sc);
        }
#pragma unroll
        for (int off = 1; off < 16; off <<= 1) {
            sn += __shfl_xor(sn, off);
            sc += __shfl_xor(sc, off);
        }
        if (l == 0) {
            nt[t] = sn;
            cJ[t] = sc;
        }
    } else {                               // ---- zero Es/Wa (128 floats)
        if (tid < 128) zbase[tid] = 0.0f;
    }
}

// Stage 1 (MFMA): grid 512 (16 t each). Wave w: m in [16w,16w+16), one 16-t tile.
// C1 = A16 * Xp16^T, C2 = A16 * Jp16^T over K=224 (7 mfma each). No LDS.
__global__ __launch_bounds__(256) void k_stage1(
    const unsigned short* __restrict__ A16, const unsigned short* __restrict__ X16,
    const unsigned short* __restrict__ J16, const float* __restrict__ nt,
    const float* __restrict__ cJ, const float* __restrict__ nx,
    unsigned short* __restrict__ w1, unsigned short* __restrict__ e1,
    float* __restrict__ EsAcc, float* __restrict__ Wacc) {
    const int tid = threadIdx.x;
    const int lane = tid & 63;
    const int w = tid >> 6;
    const int mb = w * 16;
    const int col = lane & 15, quad = lane >> 4;
    const int t0 = blockIdx.x * 16;

    const unsigned short* arow = A16 + (mb + col) * DP + quad * 8;
    const unsigned short* xrow = X16 + (size_t)(t0 + col) * DP + quad * 8;
    const unsigned short* jrow = J16 + (size_t)(t0 + col) * DP + quad * 8;

    f4 c1 = {0.f, 0.f, 0.f, 0.f};
    f4 c2 = {0.f, 0.f, 0.f, 0.f};
#pragma unroll
    for (int kc = 0; kc < 7; ++kc) {
        bf8 a  = *(const bf8*)(arow + kc * 32);
        bf8 bx = *(const bf8*)(xrow + kc * 32);
        bf8 bj = *(const bf8*)(jrow + kc * 32);
        c1 = __builtin_amdgcn_mfma_f32_16x16x32_bf16(a, bx, c1, 0, 0, 0);
        c2 = __builtin_amdgcn_mfma_f32_16x16x32_bf16(a, bj, c2, 0, 0, 0);
    }

    // epilogue: lane holds D[m=mb+quad*4+r][t=t0+col]
    const int t = t0 + col;
    const float ntv = nt[t], cjv = cJ[t];
    float esl[4], wll[4];
#pragma unroll
    for (int r = 0; r < 4; ++r) {
        const int m = mb + quad * 4 + r;
        float sq = fmaxf(nx[m] - 2.0f * c1[r] + ntv, 0.0f);
        float xd = sqrtf(sq);
        float e = KE * expf(-xd);
        float dotv = c2[r] - cjv;
        float wv = e * dotv;
        float ev = e * (1.0f + xd);
        w1[(size_t)m * NT + t] = f2bf(wv);
        e1[(size_t)m * NT + t] = f2bf(ev);
        esl[r] = ev * dotv;
        wll[r] = wv;
    }
#pragma unroll
    for (int r = 0; r < 4; ++r) {
#pragma unroll
        for (int off = 1; off < 16; off <<= 1) {
            esl[r] += __shfl_xor(esl[r], off);
            wll[r] += __shfl_xor(wll[r], off);
        }
    }
    if (col == 0) {
#pragma unroll
        for (int r = 0; r < 4; ++r) {
            atomicAdd(&EsAcc[mb + quad * 4 + r], esl[r]);
            atomicAdd(&Wacc[mb + quad * 4 + r], wll[r]);
        }
    }
}

// Stage 2 (MFMA): grid (14 d-tiles, 32 k-splits of 256 t). Wave w: m-strip 16w,
// d-tile 16. A = w1/e1 [m][t] bf16, B = XpT16/JpT16 [d][t] bf16. No LDS.
__global__ __launch_bounds__(256) void k_stage2(
    const unsigned short* __restrict__ w1, const unsigned short* __restrict__ e1,
    const unsigned short* __restrict__ XT16, const unsigned short* __restrict__ JT16,
    float* __restrict__ Pbuf) {
    const int tid = threadIdx.x;
    const int lane = tid & 63;
    const int w = tid >> 6;
    const int mb = w * 16;
    const int col = lane & 15, quad = lane >> 4;
    const int dt = blockIdx.x;
    const int t00 = blockIdx.y * 256;

    const unsigned short* awr = w1 + (size_t)(mb + col) * NT + t00 + quad * 8;
    const unsigned short* aer = e1 + (size_t)(mb + col) * NT + t00 + quad * 8;
    const unsigned short* bxr = XT16 + (size_t)(dt * 16 + col) * NT + t00 + quad * 8;
    const unsigned short* bjr = JT16 + (size_t)(dt * 16 + col) * NT + t00 + quad * 8;

    f4 dA = {0.f, 0.f, 0.f, 0.f};
    f4 dB = {0.f, 0.f, 0.f, 0.f};
#pragma unroll
    for (int kk = 0; kk < 8; ++kk) {
        bf8 aw = *(const bf8*)(awr + kk * 32);
        bf8 ae = *(const bf8*)(aer + kk * 32);
        bf8 bx = *(const bf8*)(bxr + kk * 32);
        bf8 bj = *(const bf8*)(bjr + kk * 32);
        dA = __builtin_amdgcn_mfma_f32_16x16x32_bf16(aw, bx, dA, 0, 0, 0);
        dB = __builtin_amdgcn_mfma_f32_16x16x32_bf16(ae, bj, dB, 0, 0, 0);
    }

    // Pbuf[ks][mat][m][224]; lane stores D[m=mb+quad*4+r][d=dt*16+col]
    float* p = Pbuf + (size_t)blockIdx.y * 28672 + dt * 16 + col;
#pragma unroll
    for (int r = 0; r < 4; ++r) {
        const int m = mb + quad * 4 + r;
        p[m * DP] = dA[r];
        p[14336 + m * DP] = dB[r];
    }
}

// grid 112 x 256: AB[o] = sum_ks Pbuf[ks][o], o < 28672
__global__ void k_reduce(const float* __restrict__ P, float* __restrict__ AB) {
    const int o = blockIdx.x * 256 + threadIdx.x;
    float s = 0.0f;
#pragma unroll 8
    for (int ks = 0; ks < KS2; ++ks) s += P[(size_t)ks * 28672 + o];
    AB[o] = s;
}

// grid 64 (m) x 256: expand_tril + force contraction + Es
__global__ void k_final(const float* __restrict__ Rs, const float* __restrict__ qxsG,
                        const float* __restrict__ AB, const float* __restrict__ EsAcc,
                        const float* __restrict__ Wacc, float* __restrict__ out) {
    int m = blockIdx.x, tid = threadIdx.x;
    __shared__ float R[NA * 3];
    __shared__ float Ff[NA][NA];
    if (tid < NA * 3) R[tid] = Rs[m * NA * 3 + tid];
    if (tid < NA) Ff[tid][tid] = 0.0f;
    __syncthreads();
    if (tid < ND) {
        int i, j; d_to_ij(tid, i, j);
        float dx = R[i * 3] - R[j * 3];
        float dy = R[i * 3 + 1] - R[j * 3 + 1];
        float dz = R[i * 3 + 2] - R[j * 3 + 2];
        float dist2 = dx * dx + dy * dy + dz * dz;
        float fsx = qxsG[(tid >> 2) * 256 + m * 4 + (tid & 3)] * Wacc[m]
                  - AB[(size_t)m * DP + tid]
                  - AB[14336 + (size_t)m * DP + tid];
        float f = fsx / (dist2 * sqrtf(dist2));
        Ff[i][j] = f;
        Ff[j][i] = f;
    }
    __syncthreads();
    if (tid < NA * 3) {
        int a = tid / 3, c = tid % 3;
        float s = 0.0f;
        for (int b = 0; b < NA; ++b) {
            if (b == a) continue;
            s += Ff[a][b] * (R[a * 3 + c] - R[b * 3 + c]);
        }
        out[NM + m * NA * 3 + tid] = s;
    }
    if (tid == 0) out[m] = EsAcc[m] / QC;
}

extern "C" void kernel_launch(void* const* d_in, const int* in_sizes, int n_in,
                              void* d_out, int out_size, void* d_ws, size_t ws_size,
                              hipStream_t stream) {
    const float* Rs = (const float*)d_in[0];
    const float* xs_train = (const float*)d_in[1];
    const float* Jx_alphas = (const float*)d_in[2];
    float* out = (float*)d_out;
    float* ws = (float*)d_ws;

    unsigned short* X16  = (unsigned short*)(ws + O_X16);
    unsigned short* J16  = (unsigned short*)(ws + O_J16);
    unsigned short* XT16 = (unsigned short*)(ws + O_XT16);
    unsigned short* JT16 = (unsigned short*)(ws + O_JT16);
    unsigned short* w1   = (unsigned short*)(ws + O_W1);
    unsigned short* e1   = (unsigned short*)(ws + O_E1);
    unsigned short* A16  = (unsigned short*)(ws + O_A16);
    float* qxsG  = ws + O_QG;
    float* nt    = ws + O_NTT;
    float* cJ    = ws + O_CJ;
    float* nx    = ws + O_NX;
    float* EsAcc = ws + O_ES;
    float* Wacc  = ws + O_WA;
    float* ABf   = ws + O_AB;
    float* Pbuf  = ws + O_PB;

    k_prep<<<3393, 256, 0, stream>>>(Rs, xs_train, Jx_alphas, X16, J16, XT16, JT16,
                                     A16, qxsG, nx, nt, cJ, EsAcc);
    k_stage1<<<NT / 16, 256, 0, stream>>>(A16, X16, J16, nt, cJ, nx, w1, e1, EsAcc, Wacc);
    k_stage2<<<dim3(14, KS2), 256, 0, stream>>>(w1, e1, XT16, JT16, Pbuf);
    k_reduce<<<112, 256, 0, stream>>>(Pbuf, ABf);
    k_final<<<NM, 256, 0, stream>>>(Rs, qxsG, ABf, EsAcc, Wacc, out);
}

// Round 7
// 120.792 us; speedup vs baseline: 1.2522x; 1.2522x over previous
//
#include <hip/hip_runtime.h>
#include <math.h>

#define NA   21
#define NM   64
#define ND   210
#define DP   224            // padded descriptor row
#define NT   8192
#define NCH  28             // 8-wide k-chunks per descriptor row (224/8)
#define KS2  32             // stage2 K-splits (256 t each)

#define QC 0.22360679774997896f   // sqrt(5)/10
#define KE 0.016666666666666666f  // 5/(3*sig^2)

typedef short bf8 __attribute__((ext_vector_type(8)));   // 8 bf16 (4 VGPRs)
typedef float f4  __attribute__((ext_vector_type(4)));   // 4 fp32 acc

// ---- workspace layout (float offsets); bf16 arrays count elems/2 ----
// Xf/Jf  : stage1 B frags [ttile 512][kq 28][col_t 16][8 d]   = 1835008 ush
// XfT/JfT: stage2 B frags [dtile 14][tq 1024][col_d 16][8 t]  = 1835008 ush
// w1f/e1f: stage2 A frags [mtile 4][tq 1024][col_m 16][8 t]   = 524288 ush
// Af     : stage1 A frags [mtile 4][kq 28][col_m 16][8 d]     = 14336 ush
#define O_XF   0u
#define O_JF   917504u
#define O_XFT  1835008u
#define O_JFT  2752512u
#define O_W1   3670016u
#define O_E1   3932160u
#define O_AF   4194304u        // 7168 floats
#define O_QG   4201472u        // qxsG fp32 [56][64][4] = 14336
#define O_NTT  4215808u        // nt [8192]
#define O_CJ   4224000u        // cJ [8192]
#define O_NX   4232192u        // [64]
#define O_ES   4232256u        // [64]
#define O_WA   4232320u        // [64]
#define O_AB   4232384u        // [2][64][224] fp32 = 28672
#define O_PB   4261056u        // Pbuf [32][2][64][224] fp32 = 917504 (end 5178560)

__device__ __forceinline__ unsigned short f2bf(float f) {
    unsigned u = __float_as_uint(f);
    u += 0x7fffu + ((u >> 16) & 1u);
    return (unsigned short)(u >> 16);
}
__device__ __forceinline__ float bf2f(unsigned short h) {
    return __uint_as_float((unsigned)h << 16);
}

__device__ __forceinline__ void d_to_ij(int d, int& i, int& j) {
    int ii = (int)((1.0f + sqrtf(1.0f + 8.0f * (float)d)) * 0.5f);
    while (ii * (ii - 1) / 2 > d) --ii;
    while ((ii + 1) * ii / 2 <= d) ++ii;
    i = ii;
    j = d - ii * (ii - 1) / 2;
}

// Fused prep. Roles by blockIdx.x:
//  [0,1792)      Xf/Jf  stage1-B frag layout (writes coalesced uint4)
//  [1792,2816)   XfT/JfT stage2-B frag layout via 64x64 LDS transpose
//  [2816,2880)   geom -> Af, qxsG, nx
//  [2880,4928)   rowstats -> nt, cJ (rounded-consistent)
//  [4928,4929)   zero Es/Wa
__global__ __launch_bounds__(256) void k_prep(
    const float* __restrict__ Rs, const float* __restrict__ xs,
    const float* __restrict__ Jx,
    unsigned short* __restrict__ Xf, unsigned short* __restrict__ Jf,
    unsigned short* __restrict__ XfT, unsigned short* __restrict__ JfT,
    unsigned short* __restrict__ Af, float* __restrict__ qxsG,
    float* __restrict__ nx, float* __restrict__ nt, float* __restrict__ cJ,
    float* __restrict__ zbase) {
    const int b = blockIdx.x, tid = threadIdx.x;
    if (b < 1792) {                        // ---- stage1-B frags
        const int arr = (b >= 896);
        const int ch = (b - arr * 896) * 256 + tid;     // < 229376
        const int ttile = ch / 448;
        const int rem = ch - ttile * 448;
        const int kq = rem >> 4, colt = rem & 15;
        const int t = ttile * 16 + colt, d0 = kq * 8;
        const float* src = (arr ? Jx : xs) + (size_t)t * ND + d0;
        const float sc = arr ? 1.0f : QC;
        union { unsigned short us[8]; uint4 v; } u;
#pragma unroll
        for (int i = 0; i < 8; ++i)
            u.us[i] = (d0 + i < ND) ? f2bf(sc * src[i]) : (unsigned short)0;
        *(uint4*)((arr ? Jf : Xf) + (size_t)ch * 8) = u.v;
    } else if (b < 2816) {                 // ---- stage2-B frags (transpose)
        const int bb = b - 1792;
        const int arr = (bb >= 512);
        const int r = bb - arr * 512;      // tpos(128) x dg(4)
        const int dg = r & 3, tpos = r >> 2;
        const int t0 = tpos * 64, d0 = dg * 64;
        __shared__ float tile[64][65];
        const float* src = arr ? Jx : xs;
        const float sc = arr ? 1.0f : QC;
#pragma unroll
        for (int k = 0; k < 16; ++k) {
            const int lin = k * 256 + tid;
            const int tt = lin >> 6, dd = lin & 63;
            const int d = d0 + dd;
            tile[tt][dd] = (d < ND) ? sc * src[(size_t)(t0 + tt) * ND + d] : 0.0f;
        }
        __syncthreads();
        unsigned short* dst = arr ? JfT : XfT;
        const int ndl = (dg == 3) ? 2 : 4;
#pragma unroll
        for (int k = 0; k < 2; ++k) {
            const int c = k * 256 + tid;   // 0..511
            const int dl = c >> 7, rem2 = c & 127;
            const int tql = rem2 >> 4, cl = rem2 & 15;
            if (dl < ndl) {
                union { unsigned short us[8]; uint4 v; } u;
#pragma unroll
                for (int i = 0; i < 8; ++i)
                    u.us[i] = f2bf(tile[tql * 8 + i][dl * 16 + cl]);
                const size_t off = ((size_t)((dg * 4 + dl) * 1024 + tpos * 8 + tql) * 16 + cl) * 8;
                *(uint4*)(dst + off) = u.v;
            }
        }
    } else if (b < 2880) {                 // ---- geom: m = b-2816
        const int m = b - 2816;
        __shared__ float R[NA * 3];
        __shared__ float red[256];
        if (tid < NA * 3) R[tid] = Rs[m * NA * 3 + tid];
        __syncthreads();
        float local = 0.0f;
        if (tid < DP) {
            float vr = 0.0f;
            unsigned short hv = 0;
            if (tid < ND) {
                int i, j; d_to_ij(tid, i, j);
                float dx = R[i * 3] - R[j * 3];
                float dy = R[i * 3 + 1] - R[j * 3 + 1];
                float dz = R[i * 3 + 2] - R[j * 3 + 2];
                float v = QC / sqrtf(dx * dx + dy * dy + dz * dz);
                hv = f2bf(v);
                vr = bf2f(hv);
            }
            Af[(((m >> 4) * NCH + (tid >> 3)) * 16 + (m & 15)) * 8 + (tid & 7)] = hv;
            qxsG[(tid >> 2) * 256 + m * 4 + (tid & 3)] = vr;
            local = vr * vr;
        }
        red[tid] = local;
        __syncthreads();
        for (int s = 128; s > 0; s >>= 1) {
            if (tid < s) red[tid] += red[tid + s];
            __syncthreads();
        }
        if (tid == 0) nx[m] = red[0];
    } else if (b < 4928) {                 // ---- rowstats: wave per t
        const int t = (b - 2880) * 4 + (tid >> 6);
        const int lane = tid & 63;
        const float* xr = xs + (size_t)t * ND;
        const float* jr = Jx + (size_t)t * ND;
        float sn = 0.0f, sc = 0.0f;
        for (int c = lane; c < ND; c += 64) {
            float x = bf2f(f2bf(QC * xr[c]));
            float j = bf2f(f2bf(jr[c]));
            sn = fmaf(x, x, sn);
            sc = fmaf(x, j, sc);
        }
#pragma unroll
        for (int off = 32; off > 0; off >>= 1) {
            sn += __shfl_xor(sn, off);
            sc += __shfl_xor(sc, off);
        }
        if (lane == 0) {
            nt[t] = sn;
            cJ[t] = sc;
        }
    } else {                               // ---- zero Es/Wa
        if (tid < 128) zbase[tid] = 0.0f;
    }
}

// Stage 1 (MFMA): grid 256, block = 32 t (2 ttiles) x 64 m. Wave w = mtile w.
// A panel in regs (7 bf8); B frags = contiguous 1-KB coalesced loads, depth-1
// prefetch. Epilogue transposes D via LDS -> coalesced w1f/e1f frag writes.
__global__ __launch_bounds__(256) void k_stage1(
    const unsigned short* __restrict__ Af, const unsigned short* __restrict__ Xf,
    const unsigned short* __restrict__ Jf, const float* __restrict__ nt,
    const float* __restrict__ cJ, const float* __restrict__ nx,
    unsigned short* __restrict__ w1f, unsigned short* __restrict__ e1f,
    float* __restrict__ EsAcc, float* __restrict__ Wacc) {
    const int tid = threadIdx.x;
    const int lane = tid & 63;
    const int w = tid >> 6;                // mtile
    const int col = lane & 15, quad = lane >> 4;
    __shared__ float Dw[64][17];
    __shared__ float De[64][17];

    const unsigned short* ap = Af + ((size_t)(w * NCH + quad) * 16 + col) * 8;
    bf8 af[7];
#pragma unroll
    for (int kc = 0; kc < 7; ++kc) af[kc] = *(const bf8*)(ap + kc * 512);

    float esA[4] = {0.f, 0.f, 0.f, 0.f}, wlA[4] = {0.f, 0.f, 0.f, 0.f};

    for (int tt = 0; tt < 2; ++tt) {
        const int ttile = blockIdx.x * 2 + tt;
        const unsigned short* xp = Xf + ((size_t)(ttile * NCH + quad) * 16 + col) * 8;
        const unsigned short* jp = Jf + ((size_t)(ttile * NCH + quad) * 16 + col) * 8;
        bf8 bx = *(const bf8*)xp;
        bf8 bj = *(const bf8*)jp;
        f4 c1 = {0.f, 0.f, 0.f, 0.f};
        f4 c2 = {0.f, 0.f, 0.f, 0.f};
#pragma unroll
        for (int kc = 0; kc < 7; ++kc) {
            bf8 nbx = bx, nbj = bj;
            if (kc < 6) {
                nbx = *(const bf8*)(xp + (kc + 1) * 512);
                nbj = *(const bf8*)(jp + (kc + 1) * 512);
            }
            c1 = __builtin_amdgcn_mfma_f32_16x16x32_bf16(af[kc], bx, c1, 0, 0, 0);
            c2 = __builtin_amdgcn_mfma_f32_16x16x32_bf16(af[kc], bj, c2, 0, 0, 0);
            bx = nbx; bj = nbj;
        }
        // epilogue: lane holds D[m=w*16+quad*4+r][t=ttile*16+col]
        const int t = ttile * 16 + col;
        const float ntv = nt[t], cjv = cJ[t];
#pragma unroll
        for (int r = 0; r < 4; ++r) {
            const int m = w * 16 + quad * 4 + r;
            float sq = fmaxf(nx[m] - 2.0f * c1[r] + ntv, 0.0f);
            float xd = sqrtf(sq);
            float e = KE * expf(-xd);
            float dotv = c2[r] - cjv;
            float wv = e * dotv;
            float ev = e * (1.0f + xd);
            Dw[m][col] = wv;
            De[m][col] = ev;
            esA[r] += ev * dotv;
            wlA[r] += wv;
        }
        __syncthreads();
        {   // coalesced frag-layout stores: 128 chunks per array
            const int aidx = tid >> 7;
            const int c = tid & 127;
            const int mtile = c >> 5, tql = (c >> 4) & 1, colm = c & 15;
            const float* srcD = aidx ? &De[0][0] : &Dw[0][0];
            unsigned short* dst = aidx ? e1f : w1f;
            const int m = mtile * 16 + colm;
            union { unsigned short us[8]; uint4 v; } u;
#pragma unroll
            for (int i = 0; i < 8; ++i) u.us[i] = f2bf(srcD[m * 17 + tql * 8 + i]);
            const size_t off = ((size_t)(mtile * 1024 + ttile * 2 + tql) * 16 + colm) * 8;
            *(uint4*)(dst + off) = u.v;
        }
        __syncthreads();
    }
#pragma unroll
    for (int r = 0; r < 4; ++r) {
        float e = esA[r], wl = wlA[r];
#pragma unroll
        for (int off = 1; off < 16; off <<= 1) {
            e += __shfl_xor(e, off);
            wl += __shfl_xor(wl, off);
        }
        if (col == 0) {
            atomicAdd(&EsAcc[w * 16 + quad * 4 + r], e);
            atomicAdd(&Wacc[w * 16 + quad * 4 + r], wl);
        }
    }
}

// Stage 2 (MFMA): grid (14 dtiles, 32 k-splits of 256 t). Wave w = mtile w.
// All four frag streams are contiguous coalesced 1-KB loads, depth-1 prefetch.
__global__ __launch_bounds__(256) void k_stage2(
    const unsigned short* __restrict__ w1f, const unsigned short* __restrict__ e1f,
    const unsigned short* __restrict__ XfT, const unsigned short* __restrict__ JfT,
    float* __restrict__ Pbuf) {
    const int tid = threadIdx.x;
    const int lane = tid & 63;
    const int w = tid >> 6;                // mtile
    const int col = lane & 15, quad = lane >> 4;
    const int dt = blockIdx.x;
    const int by = blockIdx.y;

    const unsigned short* awp = w1f + ((size_t)(w * 1024 + by * 32 + quad) * 16 + col) * 8;
    const unsigned short* aep = e1f + ((size_t)(w * 1024 + by * 32 + quad) * 16 + col) * 8;
    const unsigned short* bxp = XfT + ((size_t)(dt * 1024 + by * 32 + quad) * 16 + col) * 8;
    const unsigned short* bjp = JfT + ((size_t)(dt * 1024 + by * 32 + quad) * 16 + col) * 8;

    bf8 aw = *(const bf8*)awp;
    bf8 ae = *(const bf8*)aep;
    bf8 bx = *(const bf8*)bxp;
    bf8 bj = *(const bf8*)bjp;
    f4 dA = {0.f, 0.f, 0.f, 0.f};
    f4 dB = {0.f, 0.f, 0.f, 0.f};
#pragma unroll
    for (int kk = 0; kk < 8; ++kk) {
        bf8 naw = aw, nae = ae, nbx = bx, nbj = bj;
        if (kk < 7) {
            naw = *(const bf8*)(awp + (kk + 1) * 512);
            nae = *(const bf8*)(aep + (kk + 1) * 512);
            nbx = *(const bf8*)(bxp + (kk + 1) * 512);
            nbj = *(const bf8*)(bjp + (kk + 1) * 512);
        }
        dA = __builtin_amdgcn_mfma_f32_16x16x32_bf16(aw, bx, dA, 0, 0, 0);
        dB = __builtin_amdgcn_mfma_f32_16x16x32_bf16(ae, bj, dB, 0, 0, 0);
        aw = naw; ae = nae; bx = nbx; bj = nbj;
    }
    float* p = Pbuf + (size_t)by * 28672 + dt * 16 + col;
#pragma unroll
    for (int r = 0; r < 4; ++r) {
        const int m = w * 16 + quad * 4 + r;
        p[m * DP] = dA[r];
        p[14336 + m * DP] = dB[r];
    }
}

// grid 112 x 256: AB[o] = sum_ks Pbuf[ks][o], o < 28672
__global__ void k_reduce(const float* __restrict__ P, float* __restrict__ AB) {
    const int o = blockIdx.x * 256 + threadIdx.x;
    float s = 0.0f;
#pragma unroll 8
    for (int ks = 0; ks < KS2; ++ks) s += P[(size_t)ks * 28672 + o];
    AB[o] = s;
}

// grid 64 (m) x 256: expand_tril + force contraction + Es
__global__ void k_final(const float* __restrict__ Rs, const float* __restrict__ qxsG,
                        const float* __restrict__ AB, const float* __restrict__ EsAcc,
                        const float* __restrict__ Wacc, float* __restrict__ out) {
    int m = blockIdx.x, tid = threadIdx.x;
    __shared__ float R[NA * 3];
    __shared__ float Ff[NA][NA];
    if (tid < NA * 3) R[tid] = Rs[m * NA * 3 + tid];
    if (tid < NA) Ff[tid][tid] = 0.0f;
    __syncthreads();
    if (tid < ND) {
        int i, j; d_to_ij(tid, i, j);
        float dx = R[i * 3] - R[j * 3];
        float dy = R[i * 3 + 1] - R[j * 3 + 1];
        float dz = R[i * 3 + 2] - R[j * 3 + 2];
        float dist2 = dx * dx + dy * dy + dz * dz;
        float fsx = qxsG[(tid >> 2) * 256 + m * 4 + (tid & 3)] * Wacc[m]
                  - AB[(size_t)m * DP + tid]
                  - AB[14336 + (size_t)m * DP + tid];
        float f = fsx / (dist2 * sqrtf(dist2));
        Ff[i][j] = f;
        Ff[j][i] = f;
    }
    __syncthreads();
    if (tid < NA * 3) {
        int a = tid / 3, c = tid % 3;
        float s = 0.0f;
        for (int b = 0; b < NA; ++b) {
            if (b == a) continue;
            s += Ff[a][b] * (R[a * 3 + c] - R[b * 3 + c]);
        }
        out[NM + m * NA * 3 + tid] = s;
    }
    if (tid == 0) out[m] = EsAcc[m] / QC;
}

extern "C" void kernel_launch(void* const* d_in, const int* in_sizes, int n_in,
                              void* d_out, int out_size, void* d_ws, size_t ws_size,
                              hipStream_t stream) {
    const float* Rs = (const float*)d_in[0];
    const float* xs_train = (const float*)d_in[1];
    const float* Jx_alphas = (const float*)d_in[2];
    float* out = (float*)d_out;
    float* ws = (float*)d_ws;

    unsigned short* Xf  = (unsigned short*)(ws + O_XF);
    unsigned short* Jf  = (unsigned short*)(ws + O_JF);
    unsigned short* XfT = (unsigned short*)(ws + O_XFT);
    unsigned short* JfT = (unsigned short*)(ws + O_JFT);
    unsigned short* w1f = (unsigned short*)(ws + O_W1);
    unsigned short* e1f = (unsigned short*)(ws + O_E1);
    unsigned short* Af  = (unsigned short*)(ws + O_AF);
    float* qxsG  = ws + O_QG;
    float* nt    = ws + O_NTT;
    float* cJ    = ws + O_CJ;
    float* nx    = ws + O_NX;
    float* EsAcc = ws + O_ES;
    float* Wacc  = ws + O_WA;
    float* ABf   = ws + O_AB;
    float* Pbuf  = ws + O_PB;

    k_prep<<<4929, 256, 0, stream>>>(Rs, xs_train, Jx_alphas, Xf, Jf, XfT, JfT,
                                     Af, qxsG, nx, nt, cJ, EsAcc);
    k_stage1<<<256, 256, 0, stream>>>(Af, Xf, Jf, nt, cJ, nx, w1f, e1f, EsAcc, Wacc);
    k_stage2<<<dim3(14, KS2), 256, 0, stream>>>(w1f, e1f, XfT, JfT, Pbuf);
    k_reduce<<<112, 256, 0, stream>>>(Pbuf, ABf);
    k_final<<<NM, 256, 0, stream>>>(Rs, qxsG, ABf, EsAcc, Wacc, out);
}